// Round 1
// baseline (125.565 us; speedup 1.0000x reference)
//
#include <hip/hip_runtime.h>
#include <math.h>

// ChamferLoss: B=16, M=N=2048, 2-D fp32 points.
// forward_loss = mean_m min_n ||t[b,m]-a[b,n]||; backward symmetric.
// min(sqrt(x)) == sqrt(min(x)) -> inner loop on squared distances only.

#define CH_B    16
#define CH_NPTS 2048
#define THREADS 256
#define PHASES  8                 // lanes cooperating per query point
#define QPB     (THREADS / PHASES) // 32 query points per block

// One direction: for each query q[b,m], min over all r[b,n]; accumulate
// scale * sum(sqrt(min)) into *out via atomicAdd.
__global__ __launch_bounds__(THREADS) void chamfer_dir_kernel(
    const float2* __restrict__ q, const float2* __restrict__ r,
    float* __restrict__ out, float scale)
{
    __shared__ float2 spts[CH_NPTS];   // 16 KB: full reference set for batch b
    __shared__ float swave[THREADS / 64];

    const int tid = threadIdx.x;
    const int b   = blockIdx.y;

    // Stage r[b, :] into LDS with float4 (2 points per load), coalesced.
    const float4* rsrc = (const float4*)(r + (size_t)b * CH_NPTS);
    float4* dstv = (float4*)spts;
    #pragma unroll
    for (int i = 0; i < (CH_NPTS / 2) / THREADS; ++i)   // 4 iters
        dstv[tid + i * THREADS] = rsrc[tid + i * THREADS];
    __syncthreads();

    const int qi    = blockIdx.x * QPB + (tid >> 3);   // query index in batch
    const int phase = tid & (PHASES - 1);

    const float2 qp = q[(size_t)b * CH_NPTS + qi];

    float d2min = 3.4e38f;
    // Each lane covers n = phase, phase+8, ... (256 iterations).
    // Addresses within a wave: 8 distinct consecutive float2 -> banks 2p,2p+1,
    // broadcast across the 8 lanes sharing a phase: conflict-free.
    #pragma unroll 16
    for (int i = 0; i < CH_NPTS / PHASES; ++i) {
        float2 rp = spts[phase + i * PHASES];
        float dx = qp.x - rp.x;
        float dy = qp.y - rp.y;
        float d2 = dx * dx + dy * dy;
        d2min = fminf(d2min, d2);
    }

    // Min-reduce across the 8 lanes of this query.
    #pragma unroll
    for (int off = 1; off < PHASES; off <<= 1)
        d2min = fminf(d2min, __shfl_xor(d2min, off));

    float val = (phase == 0) ? sqrtf(d2min) : 0.0f;

    // Sum across the wave (64 lanes).
    #pragma unroll
    for (int off = PHASES; off < 64; off <<= 1)
        val += __shfl_xor(val, off);
    // lanes 0..7 now all hold... only phase-0 contributions; lane 0 has wave sum
    // (shfl over full width sums the masked values correctly).

    const int wave = tid >> 6;
    if ((tid & 63) == 0) swave[wave] = val;
    __syncthreads();
    if (tid == 0) {
        float s = 0.f;
        #pragma unroll
        for (int w = 0; w < THREADS / 64; ++w) s += swave[w];
        atomicAdd(out, s * scale);
    }
}

extern "C" void kernel_launch(void* const* d_in, const int* in_sizes, int n_in,
                              void* d_out, int out_size, void* d_ws, size_t ws_size,
                              hipStream_t stream) {
    const float2* tp = (const float2*)d_in[0];  // target_points [B, M, 2]
    const float2* ap = (const float2*)d_in[1];  // actual_points [B, N, 2]
    float* out = (float*)d_out;

    // d_out is re-poisoned to 0xAA before every timed launch -> zero it here.
    hipMemsetAsync(out, 0, sizeof(float), stream);

    dim3 grid(CH_NPTS / QPB, CH_B);   // 64 x 16 = 1024 blocks
    const float scale = 1.0f / (float)(CH_B * CH_NPTS);  // M == N == 2048

    // forward: target -> nearest actual
    chamfer_dir_kernel<<<grid, THREADS, 0, stream>>>(tp, ap, out, scale);
    // backward: actual -> nearest target
    chamfer_dir_kernel<<<grid, THREADS, 0, stream>>>(ap, tp, out, scale);
}

// Round 2
// 115.647 us; speedup vs baseline: 1.0858x; 1.0858x over previous
//
#include <hip/hip_runtime.h>
#include <math.h>

// ChamferLoss: B=16, M=N=2048, fp32 2-D points.
// min_n ||q - r_n||^2 = q^2 - 2 * max_n (q·r_n - ||r_n||^2/2)
// Inner loop: ds_read_b128 + fma + fma + max  (VALU-bound, inputs L2-resident).

#define CH_B     16
#define CH_NPTS  2048
#define THREADS  256
#define PHASES   8                  // lanes cooperating per query point
#define QPB      (THREADS / PHASES) // 32 queries per block
#define BLOCKS_X (CH_NPTS / QPB)    // 64
#define NPART    (BLOCKS_X * CH_B * 2) // 2048 partials (both directions)

__global__ __launch_bounds__(THREADS) void chamfer_main_kernel(
    const float2* __restrict__ tp, const float2* __restrict__ ap,
    float* __restrict__ partials)
{
    __shared__ float4 spts[CH_NPTS];     // 32 KB: (x, y, (x^2+y^2)/2, 0)
    __shared__ float  swave[THREADS / 64];

    const int tid = threadIdx.x;
    const int b   = blockIdx.y;
    const int dir = blockIdx.z;          // 0: target->actual, 1: actual->target

    const float2* q = dir ? ap : tp;
    const float2* r = dir ? tp : ap;

    // Stage reference set: float4 global loads (2 points), precompute r^2/2.
    const float4* rsrc = (const float4*)(r + (size_t)b * CH_NPTS);
    #pragma unroll
    for (int k = 0; k < (CH_NPTS / 2) / THREADS; ++k) {   // 4 iters
        float4 two = rsrc[tid + k * THREADS];
        int base = (tid + k * THREADS) * 2;
        spts[base]     = make_float4(two.x, two.y, 0.5f * (two.x*two.x + two.y*two.y), 0.f);
        spts[base + 1] = make_float4(two.z, two.w, 0.5f * (two.z*two.z + two.w*two.w), 0.f);
    }
    __syncthreads();

    const int qi    = blockIdx.x * QPB + (tid >> 3);
    const int phase = tid & (PHASES - 1);

    const float2 qp = q[(size_t)b * CH_NPTS + qi];
    const float  q2 = qp.x * qp.x + qp.y * qp.y;

    // Each lane covers n = phase, phase+8, ...  8 distinct float4 addrs per
    // wave span 128 B -> all 32 banks, 8-way broadcast: conflict-free.
    float smax = -3.4e38f;
    #pragma unroll 16
    for (int i = 0; i < CH_NPTS / PHASES; ++i) {          // 256 iters
        float4 rp = spts[phase + i * PHASES];
        smax = fmaxf(smax, fmaf(qp.x, rp.x, fmaf(qp.y, rp.y, -rp.z)));
    }

    // Max across the 8 lanes of this query.
    #pragma unroll
    for (int off = 1; off < PHASES; off <<= 1)
        smax = fmaxf(smax, __shfl_xor(smax, off));

    float val = (phase == 0) ? sqrtf(fmaxf(q2 - 2.f * smax, 0.f)) : 0.f;

    // Sum across the wave.
    #pragma unroll
    for (int off = PHASES; off < 64; off <<= 1)
        val += __shfl_xor(val, off);

    const int wave = tid >> 6;
    if ((tid & 63) == 0) swave[wave] = val;
    __syncthreads();
    if (tid == 0) {
        float s = 0.f;
        #pragma unroll
        for (int w = 0; w < THREADS / 64; ++w) s += swave[w];
        // One plain store per block -- no atomics, no cross-XCD line bouncing.
        partials[((size_t)dir * CH_B + b) * BLOCKS_X + blockIdx.x] = s;
    }
}

__global__ __launch_bounds__(256) void chamfer_reduce_kernel(
    const float* __restrict__ partials, float* __restrict__ out, float scale)
{
    __shared__ float sw[4];
    const int tid = threadIdx.x;
    const float4* p4 = (const float4*)partials;
    float s = 0.f;
    #pragma unroll
    for (int k = 0; k < (NPART / 4) / 256; ++k) {   // 2 iters
        float4 v = p4[tid + k * 256];
        s += v.x + v.y + v.z + v.w;
    }
    #pragma unroll
    for (int off = 1; off < 64; off <<= 1)
        s += __shfl_xor(s, off);
    if ((tid & 63) == 0) sw[tid >> 6] = s;
    __syncthreads();
    if (tid == 0) out[0] = (sw[0] + sw[1] + sw[2] + sw[3]) * scale;
}

extern "C" void kernel_launch(void* const* d_in, const int* in_sizes, int n_in,
                              void* d_out, int out_size, void* d_ws, size_t ws_size,
                              hipStream_t stream) {
    const float2* tp = (const float2*)d_in[0];  // target_points [B, M, 2]
    const float2* ap = (const float2*)d_in[1];  // actual_points [B, N, 2]
    float* out      = (float*)d_out;
    float* partials = (float*)d_ws;             // 2048 floats, fully overwritten

    dim3 grid(BLOCKS_X, CH_B, 2);               // 2048 blocks, both directions
    chamfer_main_kernel<<<grid, THREADS, 0, stream>>>(tp, ap, partials);

    const float scale = 1.0f / (float)(CH_B * CH_NPTS);   // M == N == 2048
    chamfer_reduce_kernel<<<1, 256, 0, stream>>>(partials, out, scale);
}

// Round 3
// 82.800 us; speedup vs baseline: 1.5165x; 1.3967x over previous
//
#include <hip/hip_runtime.h>
#include <math.h>

// ChamferLoss: B=16, M=N=2048, fp32 2-D points.
// Each lane owns one query point (VGPR); the wave sweeps reference points
// via wave-uniform indices -> compiler emits scalar s_load (SMEM pipe).
// Inner loop per ref point: v_sub, v_sub, v_mul, v_fmac, v_min — 5 VALU,
// <=1 SGPR operand each, zero LDS / zero VMEM. 4 rotating accumulators for ILP.

#define CH_B    16
#define CH_N    2048
#define QPB     128                 // queries per block
#define THREADS 256                 // 4 waves: 2 query-groups x 2 ref-halves
#define HALF    (CH_N / 2)          // refs per half-sweep
#define BLOCKS_X (CH_N / QPB)       // 16
#define NPART   (BLOCKS_X * CH_B * 2) // 512 partials

__global__ __launch_bounds__(THREADS) void chamfer_main_kernel(
    const float2* __restrict__ tp, const float2* __restrict__ ap,
    float* __restrict__ partials)
{
    __shared__ float smin[QPB];   // upper-half waves' partial mins
    __shared__ float ssum[2];

    const int tid = threadIdx.x;
    const int b   = blockIdx.y;
    const int dir = blockIdx.z;   // 0: target->actual, 1: actual->target

    const float2* q = dir ? ap : tp;
    const float*  r = (const float*)(dir ? tp : ap) + (size_t)b * CH_N * 2;

    const int qi   = blockIdx.x * QPB + (tid & (QPB - 1));
    // Which half of the reference set this wave sweeps; force wave-uniform
    // so the ref loads below are provably uniform -> s_load.
    const int half = __builtin_amdgcn_readfirstlane(tid >> 7);

    const float2 qp = q[(size_t)b * CH_N + qi];
    const float qx = qp.x, qy = qp.y;

    const float* rb = r + half * (HALF * 2);

    float a0 = 3.4e38f, a1 = 3.4e38f, a2 = 3.4e38f, a3 = 3.4e38f;
    #pragma unroll 4
    for (int j = 0; j < HALF; j += 4) {
        float rx0 = rb[2*j+0], ry0 = rb[2*j+1];
        float rx1 = rb[2*j+2], ry1 = rb[2*j+3];
        float rx2 = rb[2*j+4], ry2 = rb[2*j+5];
        float rx3 = rb[2*j+6], ry3 = rb[2*j+7];
        float dx0 = qx - rx0, dy0 = qy - ry0;
        float dx1 = qx - rx1, dy1 = qy - ry1;
        float dx2 = qx - rx2, dy2 = qy - ry2;
        float dx3 = qx - rx3, dy3 = qy - ry3;
        a0 = fminf(a0, fmaf(dy0, dy0, dx0 * dx0));
        a1 = fminf(a1, fmaf(dy1, dy1, dx1 * dx1));
        a2 = fminf(a2, fmaf(dy2, dy2, dx2 * dx2));
        a3 = fminf(a3, fmaf(dy3, dy3, dx3 * dx3));
    }
    float m = fminf(fminf(a0, a1), fminf(a2, a3));

    // Combine the two ref-halves per query through 512 B of LDS.
    if (tid >= QPB) smin[tid - QPB] = m;
    __syncthreads();
    if (tid < QPB) {
        float v = sqrtf(fminf(m, smin[tid]));
        #pragma unroll
        for (int off = 1; off < 64; off <<= 1)
            v += __shfl_xor(v, off);
        if ((tid & 63) == 0) ssum[tid >> 6] = v;
    }
    __syncthreads();
    if (tid == 0)
        partials[((size_t)dir * CH_B + b) * BLOCKS_X + blockIdx.x] =
            ssum[0] + ssum[1];
}

__global__ __launch_bounds__(64) void chamfer_reduce_kernel(
    const float* __restrict__ partials, float* __restrict__ out, float scale)
{
    const int tid = threadIdx.x;
    const float4* p4 = (const float4*)partials;   // 512 floats = 128 float4
    float4 v0 = p4[tid];
    float4 v1 = p4[tid + 64];
    float s = v0.x + v0.y + v0.z + v0.w + v1.x + v1.y + v1.z + v1.w;
    #pragma unroll
    for (int off = 1; off < 64; off <<= 1)
        s += __shfl_xor(s, off);
    if (tid == 0) out[0] = s * scale;
}

extern "C" void kernel_launch(void* const* d_in, const int* in_sizes, int n_in,
                              void* d_out, int out_size, void* d_ws, size_t ws_size,
                              hipStream_t stream) {
    const float2* tp = (const float2*)d_in[0];  // target_points [B, M, 2]
    const float2* ap = (const float2*)d_in[1];  // actual_points [B, N, 2]
    float* out      = (float*)d_out;
    float* partials = (float*)d_ws;             // 512 floats, fully overwritten

    dim3 grid(BLOCKS_X, CH_B, 2);               // 512 blocks, both directions
    chamfer_main_kernel<<<grid, THREADS, 0, stream>>>(tp, ap, partials);

    const float scale = 1.0f / (float)(CH_B * CH_N);   // M == N == 2048
    chamfer_reduce_kernel<<<1, 64, 0, stream>>>(partials, out, scale);
}

// Round 5
// 67.096 us; speedup vs baseline: 1.8714x; 1.2341x over previous
//
#include <hip/hip_runtime.h>
#include <math.h>

// ChamferLoss: B=16, M=N=2048, fp32 2-D points.
// Lane owns one query (VGPRs); wave sweeps a 256-ref slice of the LDS-staged
// reference set via WAVE-UNIFORM ds_read_b128 (same-address broadcast: no
// bank conflicts, 1 DS issue per 2 points). 8 waves/block, 1024 blocks =
// 4 blocks/CU x 8 waves = 32 waves/CU (max) to hide LDS latency.
// Per point: v_sub, v_sub, v_mul, v_fma (+ v_min3 per 2 points) = 4.5 VALU/pair.

#define CH_B    16
#define CH_N    2048
#define THREADS 512
#define WAVES   (THREADS / 64)        // 8
#define QG      64                    // queries per block (1 per lane)
#define RPW     (CH_N / WAVES)        // 256 refs per wave
#define GRID_X  (CH_N / QG)           // 32
#define NPART   (GRID_X * CH_B * 2)   // 1024 partials

__global__ __launch_bounds__(THREADS, 8) void chamfer_main_kernel(
    const float2* __restrict__ tp, const float2* __restrict__ ap,
    float* __restrict__ partials)
{
    __shared__ float2 spts[CH_N];      // 16 KB staged reference set
    __shared__ float  smin[THREADS];   // per-wave per-lane partial mins

    const int tid  = threadIdx.x;
    const int lane = tid & 63;
    const int w    = tid >> 6;
    const int b    = blockIdx.y;
    const int dir  = blockIdx.z;       // 0: target->actual, 1: actual->target

    const float2* q = dir ? ap : tp;
    const float2* r = dir ? tp : ap;

    // Per-lane query point (coalesced 8 B/lane).
    const float2 qp = q[(size_t)b * CH_N + blockIdx.x * QG + lane];
    const float qx = qp.x, qy = qp.y;

    // Stage the full reference set: 512 threads x 2 float4 (2 pts each).
    const float4* rsrc = (const float4*)(r + (size_t)b * CH_N);
    float4* sdst = (float4*)spts;
    #pragma unroll
    for (int k = 0; k < (CH_N / 2) / THREADS; ++k)      // 2 iters
        sdst[tid + k * THREADS] = rsrc[tid + k * THREADS];
    __syncthreads();

    // Sweep this wave's 256-ref slice: 128 uniform-address float4 reads.
    const float4* sp4 = (const float4*)spts + w * (RPW / 2);
    float m0 = 3.4e38f, m1 = 3.4e38f, m2 = 3.4e38f, m3 = 3.4e38f;
    #pragma unroll 2
    for (int i = 0; i < RPW / 2; i += 4) {              // 8 points / group
        float4 p0 = sp4[i + 0];
        float4 p1 = sp4[i + 1];
        float4 p2 = sp4[i + 2];
        float4 p3 = sp4[i + 3];
        float dx, dy, d2a, d2b;
        dx = qx - p0.x; dy = qy - p0.y; d2a = fmaf(dy, dy, dx * dx);
        dx = qx - p0.z; dy = qy - p0.w; d2b = fmaf(dy, dy, dx * dx);
        m0 = fminf(fminf(m0, d2a), d2b);                // -> v_min3_f32
        dx = qx - p1.x; dy = qy - p1.y; d2a = fmaf(dy, dy, dx * dx);
        dx = qx - p1.z; dy = qy - p1.w; d2b = fmaf(dy, dy, dx * dx);
        m1 = fminf(fminf(m1, d2a), d2b);
        dx = qx - p2.x; dy = qy - p2.y; d2a = fmaf(dy, dy, dx * dx);
        dx = qx - p2.z; dy = qy - p2.w; d2b = fmaf(dy, dy, dx * dx);
        m2 = fminf(fminf(m2, d2a), d2b);
        dx = qx - p3.x; dy = qy - p3.y; d2a = fmaf(dy, dy, dx * dx);
        dx = qx - p3.z; dy = qy - p3.w; d2b = fmaf(dy, dy, dx * dx);
        m3 = fminf(fminf(m3, d2a), d2b);
    }
    smin[w * 64 + lane] = fminf(fminf(m0, m1), fminf(m2, m3));
    __syncthreads();

    // Wave 0 combines the 8 slices per query, sqrt, sums across the wave.
    if (w == 0) {
        float v = smin[lane];
        #pragma unroll
        for (int j = 1; j < WAVES; ++j)
            v = fminf(v, smin[j * 64 + lane]);   // stride-64 floats: 2-way (free)
        v = sqrtf(v);
        #pragma unroll
        for (int off = 1; off < 64; off <<= 1)
            v += __shfl_xor(v, off);
        if (lane == 0)
            partials[((size_t)dir * CH_B + b) * GRID_X + blockIdx.x] = v;
    }
}

__global__ __launch_bounds__(64) void chamfer_reduce_kernel(
    const float* __restrict__ partials, float* __restrict__ out, float scale)
{
    const int tid = threadIdx.x;
    const float4* p4 = (const float4*)partials;   // 1024 floats = 256 float4
    float s = 0.f;
    #pragma unroll
    for (int k = 0; k < (NPART / 4) / 64; ++k) {  // 4 iters
        float4 v = p4[tid + k * 64];
        s += v.x + v.y + v.z + v.w;
    }
    #pragma unroll
    for (int off = 1; off < 64; off <<= 1)
        s += __shfl_xor(s, off);
    if (tid == 0) out[0] = s * scale;
}

extern "C" void kernel_launch(void* const* d_in, const int* in_sizes, int n_in,
                              void* d_out, int out_size, void* d_ws, size_t ws_size,
                              hipStream_t stream) {
    const float2* tp = (const float2*)d_in[0];  // target_points [B, M, 2]
    const float2* ap = (const float2*)d_in[1];  // actual_points [B, N, 2]
    float* out      = (float*)d_out;
    float* partials = (float*)d_ws;             // 1024 floats, fully overwritten

    dim3 grid(GRID_X, CH_B, 2);                 // 1024 blocks
    chamfer_main_kernel<<<grid, THREADS, 0, stream>>>(tp, ap, partials);

    const float scale = 1.0f / (float)(CH_B * CH_N);   // M == N == 2048
    chamfer_reduce_kernel<<<1, 64, 0, stream>>>(partials, out, scale);
}